// Round 11
// baseline (97.565 us; speedup 1.0000x reference)
//
#include <hip/hip_runtime.h>
#include <hip/hip_bf16.h>
#include <cstdint>

#define B_TOK 4096
#define DDIM  2048
#define KR    512
#define NE    8

using f32x4  = __attribute__((ext_vector_type(4))) float;
using short8 = __attribute__((ext_vector_type(8))) short;
using u16 = unsigned short;

__device__ inline u16 f2bf(float f) {
    union { float f; uint32_t u; } x; x.f = f;
    uint32_t u = x.u;
    return (u16)((u + 0x7fffu + ((u >> 16) & 1u)) >> 16);  // RNE
}
__device__ inline float bf2f(u16 h) {
    union { uint32_t u; float f; } x; x.u = ((uint32_t)h) << 16;
    return x.f;
}
__device__ inline short bfs(float f) {   // RNE via HW cvt (compiler may pack)
    __hip_bfloat16 h = __float2bfloat16(f);
    return *reinterpret_cast<short*>(&h);
}

__device__ inline void gload_lds16(const u16* g, u16* l) {
    __builtin_amdgcn_global_load_lds(
        (const __attribute__((address_space(1))) void*)g,
        (__attribute__((address_space(3))) void*)l, 16, 0, 0);
}

template<int COLS4, int SRC_LD, int DST_LD>
__device__ inline void cvt_region(const float* __restrict__ src,
                                  u16* __restrict__ dst, int i) {
    int r = i / COLS4, c = i - r * COLS4;
    float4 val = *((const float4*)(src + (size_t)r * SRC_LD) + c);
    ushort4 o;
    o.x = f2bf(val.x); o.y = f2bf(val.y); o.z = f2bf(val.z); o.w = f2bf(val.w);
    *(ushort4*)(dst + (size_t)r * DST_LD + c * 4) = o;
}

// ---- prep (tiny): V->Vb, zero rows 513..575 of Vb, u1-row = U@W1 ----
__global__ __launch_bounds__(256)
void prep_small(const float* __restrict__ U, const float* __restrict__ V,
                const float* __restrict__ W1, u16* __restrict__ Vb) {
    constexpr int NB_COPY = 64;
    constexpr int N_V = 512 * 512;           // float4 units of V
    constexpr int N_Z = 63 * 512;            // ushort4 units of zero rows
    int b = blockIdx.x;
    if (b < NB_COPY) {
        for (int i = b * 256 + threadIdx.x; i < N_V + N_Z; i += NB_COPY * 256) {
            if (i < N_V) cvt_region<512, 2048, 2048>(V, Vb, i);
            else {
                int z = i - N_V;
                ushort4 zz; zz.x = 0; zz.y = 0; zz.z = 0; zz.w = 0;
                *(ushort4*)(Vb + (size_t)513 * 2048 + (size_t)z * 4) = zz;
            }
        }
    } else {
        // u1[wrow] = U[wrow,:]·W1 ; stored as bf16 row 512 of Vb
        int wrow = (b - NB_COPY) * 4 + (threadIdx.x >> 6);
        int lane = threadIdx.x & 63;
        const float* row = U + (size_t)wrow * KR;
        float s = 0.f;
        #pragma unroll
        for (int k = 0; k < KR; k += 64) s += row[k + lane] * W1[k + lane];
        #pragma unroll
        for (int o = 32; o > 0; o >>= 1) s += __shfl_down(s, o);
        if (lane == 0) Vb[(size_t)512 * 2048 + wrow] = f2bf(s);
    }
}

// ------- router (vectorized, proven round-10) -------------------------------
__global__ __launch_bounds__(256)
void router3(const u16* __restrict__ tb, const float* __restrict__ W2,
             const float* __restrict__ lam, u16* __restrict__ Am) {
    const int row = blockIdx.x * 8 + (threadIdx.x >> 5);
    const int lr = threadIdx.x & 31;
    const u16* tr = tb + (size_t)row * 576;
    float s = bf2f(tr[512]);

    float g[NE]; float mx = -1e30f;
    #pragma unroll
    for (int e = 0; e < NE; e++) { g[e] = s * W2[e]; mx = fmaxf(mx, g[e]); }
    float den = 0.f;
    #pragma unroll
    for (int e = 0; e < NE; e++) { g[e] = expf(g[e] - mx); den += g[e]; }
    float inv = 1.0f / den;

    #pragma unroll
    for (int h = 0; h < 2; h++) {
        int k = (lr + h * 32) * 8;
        short8 tv = *(const short8*)(tr + k);
        short8 ov;
        #pragma unroll
        for (int j = 0; j < 8; j++) {
            float mu = 0.f;
            #pragma unroll
            for (int e = 0; e < NE; e++) mu += g[e] * lam[e * KR + k + j];
            ov[j] = (short)f2bf(mu * inv * bf2f((u16)tv[j]));
        }
        *(short8*)(Am + (size_t)row * 2560 + 2048 + k) = ov;
    }
}

// -------- GEMM1: A = x (f32!) staged via global_load_lds into f32 LDS;
// -------- bf16 convert on the ds_read side (cvt_pk, overlapped VALU).
// -------- f32 row = 16 chunks of 16B; swizzle c ^= (row&15) BOTH sides.
// -------- B (Vb bf16) unchanged. Copy blocks: x->Aaug, W/U->BigB (for GEMM2).
template<int NCOMP>
__global__ __launch_bounds__(256, 2)
void gemm1_f32(const float* __restrict__ xf, const u16* __restrict__ Bm,
               u16* __restrict__ Cb,
               const float* __restrict__ Wsrc, const float* __restrict__ Usrc,
               u16* __restrict__ BigB, u16* __restrict__ Aaug,
               int N, int Kc, int nbx) {
    constexpr int BM = 128, BN = 64;     // WGM=4, WGN=1 -> MF=2, NF=4
    constexpr int MF = 2, NF = 4;
    __shared__ float sAf[2 * BM * 64];   // 64 KB
    __shared__ u16   sB [2 * BN * 64];   // 16 KB  -> 80 KB total, 2 blocks/CU

    if (blockIdx.x >= NCOMP) {
        // copy role: x -> Aaug cols 0..2047 ; W -> BigB ; U -> BigB+2048
        constexpr int N_X = 4096 * 512;
        constexpr int N_W = 2048 * 512;
        constexpr int N_U = 2048 * 128;
        int cb = blockIdx.x - NCOMP;      // 0..223
        for (int i = cb * 256 + threadIdx.x; i < N_X + N_W + N_U; i += 224 * 256) {
            if (i < N_X)            cvt_region<512, 2048, 2560>(xf, Aaug, i);
            else if (i < N_X + N_W) cvt_region<512, 2048, 2560>(Wsrc, BigB, i - N_X);
            else                    cvt_region<128, 512, 2560>(Usrc, BigB + 2048, i - N_X - N_W);
        }
        return;
    }

    const int tid = threadIdx.x;
    const int wid = tid >> 6, lane = tid & 63;
    const int l15 = lane & 15, l4 = lane >> 4;
    const int wm = wid;                  // WGN=1 -> wn = 0

    const int id = ((int)blockIdx.x & 7) * (NCOMP >> 3) + ((int)blockIdx.x >> 3);
    const int row0 = (id / nbx) * BM;
    const int col0 = (id % nbx) * BN;

    // A staging (f32): thread covers (row = i*16 + tid/16, chunk tid&15);
    // pre-swizzled source chunk = (tid&15) ^ (tid>>4 & 15). i*16 keeps row&15.
    const int sra = tid >> 4;                        // 0..15
    const int sca = ((tid & 15) ^ sra) << 2;         // float offset
    const float* gA = xf + (size_t)(row0 + sra) * 2048 + sca;
    // B staging (bf16, proven): row = i*32 + tid/8, chunk (tid&7)^(row&7)
    const int srb = tid >> 3;
    const int scb = ((tid & 7) ^ (srb & 7)) << 3;
    const u16* gB = Bm + (size_t)(col0 + srb) * 2048 + scb;

    auto stageA = [&](int kt, int buf) {
        #pragma unroll
        for (int i = 0; i < 8; i++)
            gload_lds16((const u16*)(gA + (size_t)i * 16 * 2048 + kt),
                        (u16*)(sAf + buf * 8192 + i * 1024 + wid * 256));
    };
    auto stageB = [&](int kt, int buf) {
        #pragma unroll
        for (int i = 0; i < 2; i++)
            gload_lds16(gB + (size_t)i * 32 * 2048 + kt,
                        sB + buf * 4096 + i * 2048 + wid * 512);
    };

    f32x4 acc[MF][NF] = {};
    const int nt = Kc >> 6;              // 32

    stageB(0, 0);
    stageA(0, 0);
    __syncthreads();

    for (int t = 0; t < nt; ++t) {
        const int cur = t & 1;
        if (t + 1 < nt) {
            stageB((t + 1) * 64, cur ^ 1);
            stageA((t + 1) * 64, cur ^ 1);
        }
        const float* a0 = sAf + cur * 8192;
        const u16*   b0 = sB + cur * 4096;
        #pragma unroll
        for (int kc = 0; kc < 8; kc += 4) {
            short8 af[MF], bv[NF];
            #pragma unroll
            for (int mf = 0; mf < MF; mf++) {
                int row = wm * 32 + mf * 16 + l15;     // row&15 == l15
                int g = kc + l4;                       // k-group of 8
                int c0 = (2 * g) ^ l15;
                int c1 = (2 * g + 1) ^ l15;
                f32x4 p0 = *(const f32x4*)(a0 + row * 64 + c0 * 4);
                f32x4 p1 = *(const f32x4*)(a0 + row * 64 + c1 * 4);
                short8 h;
                h[0] = bfs(p0[0]); h[1] = bfs(p0[1]);
                h[2] = bfs(p0[2]); h[3] = bfs(p0[3]);
                h[4] = bfs(p1[0]); h[5] = bfs(p1[1]);
                h[6] = bfs(p1[2]); h[7] = bfs(p1[3]);
                af[mf] = h;
            }
            #pragma unroll
            for (int nf = 0; nf < NF; nf++) {
                int row = nf * 16 + l15;               // wn = 0
                int ch = (kc + l4) ^ (row & 7);
                bv[nf] = *(const short8*)(b0 + row * 64 + ch * 8);
            }
            #pragma unroll
            for (int mf = 0; mf < MF; mf++)
                #pragma unroll
                for (int nf = 0; nf < NF; nf++)
                    acc[mf][nf] = __builtin_amdgcn_mfma_f32_16x16x32_bf16(
                        af[mf], bv[nf], acc[mf][nf], 0, 0, 0);
        }
        __syncthreads();
    }

    #pragma unroll
    for (int nf = 0; nf < NF; nf++) {
        int col = col0 + nf * 16 + l15;
        #pragma unroll
        for (int mf = 0; mf < MF; mf++) {
            int row = row0 + wm * 32 + mf * 16 + l4 * 4;
            #pragma unroll
            for (int r2 = 0; r2 < 4; r2++)
                Cb[(size_t)(row + r2) * N + col] = f2bf(acc[mf][nf][r2]);
        }
    }
}

// ---- GEMM2: 256x128 tile, BK=64, 3-slot LDS ring, counted vmcnt(6) gates,
// ---- raw s_barrier, setprio, T2 swizzle, REGION XCD tiling (proven engine).
template<bool HAS_V>
__global__ __launch_bounds__(512, 1)
void gemm_ring(const u16* __restrict__ A, const u16* __restrict__ Bm,
               float* __restrict__ C, const float* __restrict__ v,
               int N, int Kc, int lda, int ldb) {
    constexpr int BM = 256, BN = 128, WGN = 2;
    constexpr int MF = 4, NF = 4;
    constexpr int SLOT = (BM + BN) * 64;        // 48KB per ring slot
    constexpr int ROWS = 64;
    constexpr int ISSA = 4, ISSB = 2;
    __shared__ u16 lds[3 * SLOT];               // 144 KB

    const int tid = threadIdx.x;
    const int wid = tid >> 6, lane = tid & 63;
    const int l15 = lane & 15, l4 = lane >> 4;
    const int wm = wid / WGN, wn = wid % WGN;

    // REGION: grid 256 = 16x16 tiles; XCD x -> rows [(x>>1)*4..+4), cols [(x&1)*8..+8)
    const int xcd = blockIdx.x & 7;
    const int j = blockIdx.x >> 3;              // 0..31
    const int row0 = ((xcd >> 1) * 4 + (j >> 3)) * BM;
    const int col0 = ((xcd & 1) * 8 + (j & 7)) * BN;

    const int srow = tid >> 3;
    const int scol = ((tid & 7) ^ (srow & 7)) << 3;
    const u16* gA = A + (size_t)(row0 + srow) * lda + scol;
    const u16* gB = Bm + (size_t)(col0 + srow) * ldb + scol;

    // hoisted fragment byte-offsets (t-invariant; only slot base changes)
    int aoff[2][MF], boff[2][NF];
    #pragma unroll
    for (int kc = 0; kc < 2; kc++) {
        #pragma unroll
        for (int mf = 0; mf < MF; mf++) {
            int row = wm * MF * 16 + mf * 16 + l15;
            aoff[kc][mf] = row * 64 + (((kc * 4) + l4) ^ (row & 7)) * 8;
        }
        #pragma unroll
        for (int nf = 0; nf < NF; nf++) {
            int row = wn * NF * 16 + nf * 16 + l15;
            boff[kc][nf] = BM * 64 + row * 64 + (((kc * 4) + l4) ^ (row & 7)) * 8;
        }
    }

    f32x4 acc[MF][NF] = {};
    const int nt = Kc >> 6;

    #pragma unroll
    for (int p = 0; p < 2; p++) {
        const u16* gAt = gA + p * 64;
        const u16* gBt = gB + p * 64;
        u16* sl = lds + p * SLOT;
        #pragma unroll
        for (int i = 0; i < ISSA; i++)
            gload_lds16(gAt + (size_t)i * ROWS * lda,
                        sl + i * ROWS * 64 + wid * 512);
        #pragma unroll
        for (int i = 0; i < ISSB; i++)
            gload_lds16(gBt + (size_t)i * ROWS * ldb,
                        sl + BM * 64 + i * ROWS * 64 + wid * 512);
    }
    asm volatile("s_waitcnt vmcnt(6)" ::: "memory");   // tile 0 resident
    __builtin_amdgcn_s_barrier();
    asm volatile("" ::: "memory");

    int sc = 0, sp = 2;   // slot of tile t / tile t+2
    for (int t = 0; t < nt; ++t) {
        if (t + 2 < nt) {
            const u16* gAt = gA + (size_t)(t + 2) * 64;
            const u16* gBt = gB + (size_t)(t + 2) * 64;
            u16* sl = lds + sp * SLOT;
            #pragma unroll
            for (int i = 0; i < ISSA; i++)
                gload_lds16(gAt + (size_t)i * ROWS * lda,
                            sl + i * ROWS * 64 + wid * 512);
            #pragma unroll
            for (int i = 0; i < ISSB; i++)
                gload_lds16(gBt + (size_t)i * ROWS * ldb,
                            sl + BM * 64 + i * ROWS * 64 + wid * 512);
        }
        const u16* s0 = lds + sc * SLOT;
        __builtin_amdgcn_s_setprio(1);
        #pragma unroll
        for (int kc = 0; kc < 2; kc++) {
            short8 af[MF], bv[NF];
            #pragma unroll
            for (int mf = 0; mf < MF; mf++)
                af[mf] = *(const short8*)(s0 + aoff[kc][mf]);
            #pragma unroll
            for (int nf = 0; nf < NF; nf++)
                bv[nf] = *(const short8*)(s0 + boff[kc][nf]);
            #pragma unroll
            for (int mf = 0; mf < MF; mf++)
                #pragma unroll
                for (int nf = 0; nf < NF; nf++)
                    acc[mf][nf] = __builtin_amdgcn_mfma_f32_16x16x32_bf16(
                        af[mf], bv[nf], acc[mf][nf], 0, 0, 0);
        }
        __builtin_amdgcn_s_setprio(0);

        const int rem = nt - 1 - t;
        if (rem == 0) break;
        if (rem >= 2) asm volatile("s_waitcnt vmcnt(6)" ::: "memory");
        else          asm volatile("s_waitcnt vmcnt(0)" ::: "memory");
        __builtin_amdgcn_s_barrier();
        asm volatile("" ::: "memory");
        sc = (sc == 2) ? 0 : sc + 1;
        sp = (sp == 2) ? 0 : sp + 1;
    }

    #pragma unroll
    for (int nf = 0; nf < NF; nf++) {
        int col = col0 + wn * NF * 16 + nf * 16 + l15;
        float sc2 = HAS_V ? (1.0f + v[col]) : 1.0f;
        #pragma unroll
        for (int mf = 0; mf < MF; mf++) {
            int row = row0 + wm * MF * 16 + mf * 16 + l4 * 4;
            #pragma unroll
            for (int r2 = 0; r2 < 4; r2++)
                C[(size_t)(row + r2) * N + col] = acc[mf][nf][r2] * sc2;
        }
    }
}

extern "C" void kernel_launch(void* const* d_in, const int* in_sizes, int n_in,
                              void* d_out, int out_size, void* d_ws, size_t ws_size,
                              hipStream_t stream) {
    const float* x   = (const float*)d_in[0];
    const float* W   = (const float*)d_in[1];
    const float* U   = (const float*)d_in[2];
    const float* V   = (const float*)d_in[3];
    const float* lam = (const float*)d_in[4];
    const float* v   = (const float*)d_in[5];
    const float* W1  = (const float*)d_in[6];
    const float* W2  = (const float*)d_in[7];
    float* out = (float*)d_out;

    char* ws = (char*)d_ws;
    u16* Aaug  = (u16*)ws;                       // 4096 x 2560 bf16 (x | m)
    u16* BigB  = (u16*)(ws + 20971520);          // 2048 x 2560 bf16 (W | U)
    u16* Vb    = (u16*)(ws + 31457280);          // 576 x 2048 bf16 (V ; u1 ; 0)
    u16* tmatb = (u16*)(ws + 33816576);          // 4096 x 576 bf16 (t | s)

    // tiny prep: V conversion + Vb zero rows + u1 row
    prep_small<<<576, 256, 0, stream>>>(U, V, W1, Vb);

    // GEMM1 (288 compute blocks, A = x f32 direct via gload_lds + read-side cvt)
    // + 224 copy blocks (x->Aaug, W/U->BigB, all for GEMM2)
    gemm1_f32<288><<<512, 256, 0, stream>>>(
        x, Vb, tmatb, W, U, BigB, Aaug, 576, 2048, 9);

    // router: softmax(s*W2) -> m into Aaug[:, 2048:2560]
    router3<<<512, 256, 0, stream>>>(tmatb, W2, lam, Aaug);

    // GEMM2: out(4096x2048) = [xb|m] @ [W|U]^T, K=2560. grid 16x16 = 256.
    gemm_ring<true><<<256, 512, 0, stream>>>(
        Aaug, BigB, out, v, 2048, 2560, 2560, 2560);
}

// Round 12
// 91.480 us; speedup vs baseline: 1.0665x; 1.0665x over previous
//
#include <hip/hip_runtime.h>
#include <hip/hip_bf16.h>
#include <cstdint>

#define B_TOK 4096
#define DDIM  2048
#define KR    512
#define NE    8

using f32x4  = __attribute__((ext_vector_type(4))) float;
using short8 = __attribute__((ext_vector_type(8))) short;
using u16 = unsigned short;

__device__ inline u16 f2bf(float f) {
    union { float f; uint32_t u; } x; x.f = f;
    uint32_t u = x.u;
    return (u16)((u + 0x7fffu + ((u >> 16) & 1u)) >> 16);  // RNE
}
__device__ inline float bf2f(u16 h) {
    union { uint32_t u; float f; } x; x.u = ((uint32_t)h) << 16;
    return x.f;
}

__device__ inline void gload_lds16(const u16* g, u16* l) {
    __builtin_amdgcn_global_load_lds(
        (const __attribute__((address_space(1))) void*)g,
        (__attribute__((address_space(3))) void*)l, 16, 0, 0);
}

template<int COLS4, int SRC_LD, int DST_LD>
__device__ inline void cvt_region(const float* __restrict__ src,
                                  u16* __restrict__ dst, int i) {
    int r = i / COLS4, c = i - r * COLS4;
    float4 val = *((const float4*)(src + (size_t)r * SRC_LD) + c);
    ushort4 o;
    o.x = f2bf(val.x); o.y = f2bf(val.y); o.z = f2bf(val.z); o.w = f2bf(val.w);
    *(ushort4*)(dst + (size_t)r * DST_LD + c * 4) = o;
}

// ---- prep: x->Aaug, V->Vb, zero rows 513..575 of Vb, u1-row = U@W1 ----
__global__ __launch_bounds__(256)
void prep_all(const float* __restrict__ x, const float* __restrict__ U,
              const float* __restrict__ V, const float* __restrict__ W1,
              u16* __restrict__ Aaug, u16* __restrict__ Vb) {
    constexpr int NB_COPY = 1024;
    constexpr int N_X = 4096 * 512;
    constexpr int N_V = 512 * 512;
    constexpr int N_Z = 63 * 512;            // zero rows 513..575 of Vb
    constexpr int N_TOT = N_X + N_V + N_Z;
    int b = blockIdx.x;
    if (b < NB_COPY) {
        for (int i = b * 256 + threadIdx.x; i < N_TOT; i += NB_COPY * 256) {
            if (i < N_X)            cvt_region<512, 2048, 2560>(x, Aaug, i);
            else if (i < N_X + N_V) cvt_region<512, 2048, 2048>(V, Vb, i - N_X);
            else {
                int z = i - (N_X + N_V);
                ushort4 zz; zz.x = 0; zz.y = 0; zz.z = 0; zz.w = 0;
                *(ushort4*)(Vb + (size_t)513 * 2048 + (size_t)z * 4) = zz;
            }
        }
    } else {
        // u1[wrow] = U[wrow,:]·W1 ; stored as bf16 row 512 of Vb
        int wrow = (b - NB_COPY) * 4 + (threadIdx.x >> 6);
        int lane = threadIdx.x & 63;
        const float* row = U + (size_t)wrow * KR;
        float s = 0.f;
        #pragma unroll
        for (int k = 0; k < KR; k += 64) s += row[k + lane] * W1[k + lane];
        #pragma unroll
        for (int o = 32; o > 0; o >>= 1) s += __shfl_down(s, o);
        if (lane == 0) Vb[(size_t)512 * 2048 + wrow] = f2bf(s);
    }
}

// ------- router (vectorized): 8 rows/block, short8 loads/stores ----------
// s = t[:,512] ; g = softmax(s*W2) ; m = (g.lam)*inv * t -> Aaug[:,2048:2560]
__global__ __launch_bounds__(256)
void router3(const u16* __restrict__ tb, const float* __restrict__ W2,
             const float* __restrict__ lam, u16* __restrict__ Am) {
    const int row = blockIdx.x * 8 + (threadIdx.x >> 5);
    const int lr = threadIdx.x & 31;
    const u16* tr = tb + (size_t)row * 576;
    float s = bf2f(tr[512]);

    float g[NE]; float mx = -1e30f;
    #pragma unroll
    for (int e = 0; e < NE; e++) { g[e] = s * W2[e]; mx = fmaxf(mx, g[e]); }
    float den = 0.f;
    #pragma unroll
    for (int e = 0; e < NE; e++) { g[e] = expf(g[e] - mx); den += g[e]; }
    float inv = 1.0f / den;

    #pragma unroll
    for (int h = 0; h < 2; h++) {
        int k = (lr + h * 32) * 8;              // unit of 8 k's
        short8 tv = *(const short8*)(tr + k);
        short8 ov;
        #pragma unroll
        for (int j = 0; j < 8; j++) {
            float mu = 0.f;
            #pragma unroll
            for (int e = 0; e < NE; e++) mu += g[e] * lam[e * KR + k + j];
            ov[j] = (short)f2bf(mu * inv * bf2f((u16)tv[j]));
        }
        *(short8*)(Am + (size_t)row * 2560 + 2048 + k) = ov;
    }
}

// -------- GEMM1 (round-2 proven, 2-buffer BK=64) + fused W/U copy blocks ----
// Blocks [0, NCOMP) compute; blocks [NCOMP, NCOMP+256) convert W,U -> BigB.
template<int BM, int BN, int WGM, int WGN, int NCOMP, bool OUT_BF16>
__global__ __launch_bounds__(256, 2)
void gemm_db(const u16* __restrict__ A, const u16* __restrict__ Bm,
             void* __restrict__ Cv,
             const float* __restrict__ Wsrc, const float* __restrict__ Usrc,
             u16* __restrict__ BigB,
             int N, int Kc, int lda, int ldb, int nbx) {
    constexpr int MF = BM / (WGM * 16);
    constexpr int NF = BN / (WGN * 16);
    constexpr int ISSA = BM / 32;
    constexpr int ISSB = BN / 32;
    __shared__ u16 sA[2 * BM * 64];
    __shared__ u16 sB[2 * BN * 64];

    if (blockIdx.x >= NCOMP) {
        constexpr int N_W = 2048 * 512;   // float4 units
        constexpr int N_U = 2048 * 128;
        int cb = blockIdx.x - NCOMP;      // 0..255
        for (int i = cb * 256 + threadIdx.x; i < N_W + N_U; i += 256 * 256) {
            if (i < N_W) cvt_region<512, 2048, 2560>(Wsrc, BigB, i);
            else         cvt_region<128, 512, 2560>(Usrc, BigB + 2048, i - N_W);
        }
        return;
    }

    const int tid = threadIdx.x;
    const int wid = tid >> 6, lane = tid & 63;
    const int l15 = lane & 15, l4 = lane >> 4;
    const int wm = wid / WGN, wn = wid % WGN;

    const int id = ((int)blockIdx.x & 7) * (NCOMP >> 3) + ((int)blockIdx.x >> 3);
    const int row0 = (id / nbx) * BM;
    const int col0 = (id % nbx) * BN;

    const int srow = tid >> 3;
    const int scol = ((tid & 7) ^ (srow & 7)) << 3;
    const u16* gA = A + (size_t)(row0 + srow) * lda + scol;
    const u16* gB = Bm + (size_t)(col0 + srow) * ldb + scol;

    f32x4 acc[MF][NF] = {};
    const int nt = Kc >> 6;

    #pragma unroll
    for (int i = 0; i < ISSA; i++)
        gload_lds16(gA + (size_t)i * 32 * lda, sA + i * 2048 + wid * 512);
    #pragma unroll
    for (int i = 0; i < ISSB; i++)
        gload_lds16(gB + (size_t)i * 32 * ldb, sB + i * 2048 + wid * 512);
    __syncthreads();

    for (int t = 0; t < nt; ++t) {
        const int cur = t & 1;
        if (t + 1 < nt) {
            const int nxt = cur ^ 1;
            const u16* gAk = gA + (size_t)(t + 1) * 64;
            const u16* gBk = gB + (size_t)(t + 1) * 64;
            #pragma unroll
            for (int i = 0; i < ISSA; i++)
                gload_lds16(gAk + (size_t)i * 32 * lda,
                            sA + nxt * BM * 64 + i * 2048 + wid * 512);
            #pragma unroll
            for (int i = 0; i < ISSB; i++)
                gload_lds16(gBk + (size_t)i * 32 * ldb,
                            sB + nxt * BN * 64 + i * 2048 + wid * 512);
        }
        const u16* a0 = sA + cur * BM * 64;
        const u16* b0 = sB + cur * BN * 64;
        #pragma unroll
        for (int kc = 0; kc < 8; kc += 4) {
            short8 af[MF], bv[NF];
            #pragma unroll
            for (int mf = 0; mf < MF; mf++) {
                int row = wm * MF * 16 + mf * 16 + l15;
                int ch = (kc + l4) ^ (row & 7);
                af[mf] = *(const short8*)(a0 + row * 64 + ch * 8);
            }
            #pragma unroll
            for (int nf = 0; nf < NF; nf++) {
                int row = wn * NF * 16 + nf * 16 + l15;
                int ch = (kc + l4) ^ (row & 7);
                bv[nf] = *(const short8*)(b0 + row * 64 + ch * 8);
            }
            #pragma unroll
            for (int mf = 0; mf < MF; mf++)
                #pragma unroll
                for (int nf = 0; nf < NF; nf++)
                    acc[mf][nf] = __builtin_amdgcn_mfma_f32_16x16x32_bf16(
                        af[mf], bv[nf], acc[mf][nf], 0, 0, 0);
        }
        __syncthreads();
    }

    #pragma unroll
    for (int nf = 0; nf < NF; nf++) {
        int col = col0 + wn * NF * 16 + nf * 16 + l15;
        #pragma unroll
        for (int mf = 0; mf < MF; mf++) {
            int row = row0 + wm * MF * 16 + mf * 16 + l4 * 4;
            #pragma unroll
            for (int r2 = 0; r2 < 4; r2++) {
                float val = acc[mf][nf][r2];
                if constexpr (OUT_BF16)
                    ((u16*)Cv)[(size_t)(row + r2) * N + col] = f2bf(val);
                else
                    ((float*)Cv)[(size_t)(row + r2) * N + col] = val;
            }
        }
    }
}

// ---- GEMM2: 256x128 tile, BK=64, 3-slot LDS ring, counted vmcnt(6) gates,
// ---- raw s_barrier, setprio, T2 swizzle, REGION XCD tiling (proven engine).
template<bool HAS_V>
__global__ __launch_bounds__(512, 1)
void gemm_ring(const u16* __restrict__ A, const u16* __restrict__ Bm,
               float* __restrict__ C, const float* __restrict__ v,
               int N, int Kc, int lda, int ldb) {
    constexpr int BM = 256, BN = 128, WGN = 2;
    constexpr int MF = 4, NF = 4;
    constexpr int SLOT = (BM + BN) * 64;        // 48KB per ring slot
    constexpr int ROWS = 64;
    constexpr int ISSA = 4, ISSB = 2;
    __shared__ u16 lds[3 * SLOT];               // 144 KB

    const int tid = threadIdx.x;
    const int wid = tid >> 6, lane = tid & 63;
    const int l15 = lane & 15, l4 = lane >> 4;
    const int wm = wid / WGN, wn = wid % WGN;

    // REGION: grid 256 = 16x16 tiles; XCD x -> rows [(x>>1)*4..+4), cols [(x&1)*8..+8)
    const int xcd = blockIdx.x & 7;
    const int j = blockIdx.x >> 3;              // 0..31
    const int row0 = ((xcd >> 1) * 4 + (j >> 3)) * BM;
    const int col0 = ((xcd & 1) * 8 + (j & 7)) * BN;

    const int srow = tid >> 3;
    const int scol = ((tid & 7) ^ (srow & 7)) << 3;
    const u16* gA = A + (size_t)(row0 + srow) * lda + scol;
    const u16* gB = Bm + (size_t)(col0 + srow) * ldb + scol;

    // hoisted fragment byte-offsets (t-invariant; only slot base changes)
    int aoff[2][MF], boff[2][NF];
    #pragma unroll
    for (int kc = 0; kc < 2; kc++) {
        #pragma unroll
        for (int mf = 0; mf < MF; mf++) {
            int row = wm * MF * 16 + mf * 16 + l15;
            aoff[kc][mf] = row * 64 + (((kc * 4) + l4) ^ (row & 7)) * 8;
        }
        #pragma unroll
        for (int nf = 0; nf < NF; nf++) {
            int row = wn * NF * 16 + nf * 16 + l15;
            boff[kc][nf] = BM * 64 + row * 64 + (((kc * 4) + l4) ^ (row & 7)) * 8;
        }
    }

    f32x4 acc[MF][NF] = {};
    const int nt = Kc >> 6;

    #pragma unroll
    for (int p = 0; p < 2; p++) {
        const u16* gAt = gA + p * 64;
        const u16* gBt = gB + p * 64;
        u16* sl = lds + p * SLOT;
        #pragma unroll
        for (int i = 0; i < ISSA; i++)
            gload_lds16(gAt + (size_t)i * ROWS * lda,
                        sl + i * ROWS * 64 + wid * 512);
        #pragma unroll
        for (int i = 0; i < ISSB; i++)
            gload_lds16(gBt + (size_t)i * ROWS * ldb,
                        sl + BM * 64 + i * ROWS * 64 + wid * 512);
    }
    asm volatile("s_waitcnt vmcnt(6)" ::: "memory");   // tile 0 resident
    __builtin_amdgcn_s_barrier();
    asm volatile("" ::: "memory");

    int sc = 0, sp = 2;   // slot of tile t / tile t+2
    for (int t = 0; t < nt; ++t) {
        if (t + 2 < nt) {
            const u16* gAt = gA + (size_t)(t + 2) * 64;
            const u16* gBt = gB + (size_t)(t + 2) * 64;
            u16* sl = lds + sp * SLOT;
            #pragma unroll
            for (int i = 0; i < ISSA; i++)
                gload_lds16(gAt + (size_t)i * ROWS * lda,
                            sl + i * ROWS * 64 + wid * 512);
            #pragma unroll
            for (int i = 0; i < ISSB; i++)
                gload_lds16(gBt + (size_t)i * ROWS * ldb,
                            sl + BM * 64 + i * ROWS * 64 + wid * 512);
        }
        const u16* s0 = lds + sc * SLOT;
        __builtin_amdgcn_s_setprio(1);
        #pragma unroll
        for (int kc = 0; kc < 2; kc++) {
            short8 af[MF], bv[NF];
            #pragma unroll
            for (int mf = 0; mf < MF; mf++)
                af[mf] = *(const short8*)(s0 + aoff[kc][mf]);
            #pragma unroll
            for (int nf = 0; nf < NF; nf++)
                bv[nf] = *(const short8*)(s0 + boff[kc][nf]);
            #pragma unroll
            for (int mf = 0; mf < MF; mf++)
                #pragma unroll
                for (int nf = 0; nf < NF; nf++)
                    acc[mf][nf] = __builtin_amdgcn_mfma_f32_16x16x32_bf16(
                        af[mf], bv[nf], acc[mf][nf], 0, 0, 0);
        }
        __builtin_amdgcn_s_setprio(0);

        const int rem = nt - 1 - t;
        if (rem == 0) break;
        if (rem >= 2) asm volatile("s_waitcnt vmcnt(6)" ::: "memory");
        else          asm volatile("s_waitcnt vmcnt(0)" ::: "memory");
        __builtin_amdgcn_s_barrier();
        asm volatile("" ::: "memory");
        sc = (sc == 2) ? 0 : sc + 1;
        sp = (sp == 2) ? 0 : sp + 1;
    }

    #pragma unroll
    for (int nf = 0; nf < NF; nf++) {
        int col = col0 + wn * NF * 16 + nf * 16 + l15;
        float sc2 = HAS_V ? (1.0f + v[col]) : 1.0f;
        #pragma unroll
        for (int mf = 0; mf < MF; mf++) {
            int row = row0 + wm * MF * 16 + mf * 16 + l4 * 4;
            #pragma unroll
            for (int r2 = 0; r2 < 4; r2++)
                C[(size_t)(row + r2) * N + col] = acc[mf][nf][r2] * sc2;
        }
    }
}

extern "C" void kernel_launch(void* const* d_in, const int* in_sizes, int n_in,
                              void* d_out, int out_size, void* d_ws, size_t ws_size,
                              hipStream_t stream) {
    const float* x   = (const float*)d_in[0];
    const float* W   = (const float*)d_in[1];
    const float* U   = (const float*)d_in[2];
    const float* V   = (const float*)d_in[3];
    const float* lam = (const float*)d_in[4];
    const float* v   = (const float*)d_in[5];
    const float* W1  = (const float*)d_in[6];
    const float* W2  = (const float*)d_in[7];
    float* out = (float*)d_out;

    char* ws = (char*)d_ws;
    u16* Aaug  = (u16*)ws;                       // 4096 x 2560 bf16 (x | m)
    u16* BigB  = (u16*)(ws + 20971520);          // 2048 x 2560 bf16 (W | U)
    u16* Vb    = (u16*)(ws + 31457280);          // 576 x 2048 bf16 (V ; u1 ; 0)
    u16* tmatb = (u16*)(ws + 33816576);          // 4096 x 576 bf16 (t | s)

    // prep: x,V conversions + Vb zero rows + u1 row (1536 blocks)
    prep_all<<<1536, 256, 0, stream>>>(x, U, V, W1, Aaug, Vb);

    // GEMM1 (288 compute blocks) + fused W/U->BigB conversion (256 copy blocks)
    gemm_db<128, 64, 4, 1, 288, true><<<544, 256, 0, stream>>>(
        Aaug, Vb, tmatb, W, U, BigB, 576, 2048, 2560, 2048, 9);

    // router: softmax(s*W2) -> m into Aaug[:, 2048:2560] (vectorized)
    router3<<<512, 256, 0, stream>>>(tmatb, W2, lam, Aaug);

    // GEMM2: out(4096x2048) = [xb|m] @ [W|U]^T, K=2560. grid 16x16 = 256.
    gemm_ring<true><<<256, 512, 0, stream>>>(
        Aaug, BigB, out, v, 2048, 2560, 2560, 2560);
}